// Round 4
// baseline (551.582 us; speedup 1.0000x reference)
//
#include <hip/hip_runtime.h>
#include <hip/hip_bf16.h>
#include <stdint.h>

// Complex-valued MHA: B=2, S=2048, D=512, H=8, DK=64
#define Bb 2
#define Ss 2048
#define Dd 512
#define Hh 8
#define DKk 64

// sizes (elements)
#define NROW 4096            // B*S
#define MAT_E 2097152        // B*S*D
#define W_E 262144           // D*D

typedef __attribute__((ext_vector_type(8))) short short8;
typedef __attribute__((ext_vector_type(4))) float f32x4;

__device__ __forceinline__ unsigned short f2bf(float f) {
  union { float f; uint32_t u; } v; v.f = f;
  uint32_t u = v.u;
  uint32_t r = u + 0x7FFFu + ((u >> 16) & 1u);   // round-to-nearest-even
  return (unsigned short)(r >> 16);
}

// ---------------- 1a. convert activations fp32 -> bf16 ----------------
__global__ __launch_bounds__(256) void ck_cvt_in(
    const float* __restrict__ a0, const float* __restrict__ a1,
    const float* __restrict__ a2, const float* __restrict__ a3,
    const float* __restrict__ a4, const float* __restrict__ a5,
    unsigned short* __restrict__ out)
{
  int z = blockIdx.y;
  const float* src = z==0?a0: z==1?a1: z==2?a2: z==3?a3: z==4?a4: a5;
  unsigned short* dst = out + (size_t)z * MAT_E;
  int i = blockIdx.x * 256 + threadIdx.x;          // 2048*256*4 = MAT_E
  float4 v = ((const float4*)src)[i];
  unsigned short o[4] = {f2bf(v.x), f2bf(v.y), f2bf(v.z), f2bf(v.w)};
  *((uint2*)(dst + (size_t)i * 4)) = *((uint2*)o);
}

// ---------------- 1b. convert + transpose weights: Wt[d][k] = w[k][d] ----
__global__ __launch_bounds__(256) void ck_cvt_wt(
    const float* __restrict__ w0, const float* __restrict__ w1,
    const float* __restrict__ w2, const float* __restrict__ w3,
    unsigned short* __restrict__ out)
{
  int z = blockIdx.y;
  const float* w = z==0?w0: z==1?w1: z==2?w2: w3;
  unsigned short* wt = out + (size_t)z * W_E;
  int t = blockIdx.x * 256 + threadIdx.x;          // t = d*512 + k
  int d = t >> 9, k = t & 511;
  wt[t] = f2bf(w[k * 512 + d]);                    // strided read (L2-cached), coalesced write
}

// ---------------- 1c. pack mask int32 -> 64-bit words (1 bit per k) -------
__global__ __launch_bounds__(256) void ck_mask_pack(
    const int* __restrict__ mask, unsigned long long* __restrict__ mb)
{
  size_t i = (size_t)blockIdx.x * 256 + threadIdx.x;   // B*S*S threads
  int v = mask[i];
  unsigned long long bits = __ballot(v != 0);
  if ((threadIdx.x & 63) == 0) mb[i >> 6] = bits;
}

// ---------------- 2. projection GEMM ----------------
// z: 0=qr(wq) 1=kr(wk) 2=vr(wv,transposed out) 3=qp(wq) 4=kp(wk) 5=vp(wv,transposed)
__device__ const size_t PROJ_OFF[6] = {0, 2097152, 8388608, 4194304, 6291456, 10485760};

__global__ __launch_bounds__(256) void ck_proj_gemm(
    const unsigned short* __restrict__ xb,   // 6 x [4096,512] bf16
    const unsigned short* __restrict__ wt,   // 4 x [512,512] bf16 (transposed)
    unsigned short* __restrict__ proj)
{
  int z = blockIdx.z;
  int wsel = z % 3;
  const unsigned short* A = xb + (size_t)z * MAT_E;
  const unsigned short* W = wt + (size_t)wsel * W_E;

  int wave = threadIdx.x >> 6, lane = threadIdx.x & 63;
  int lo = lane & 15, hi = lane >> 4;
  int m0 = blockIdx.x * 64 + wave * 16;
  int n0 = blockIdx.y * 64;

  f32x4 acc[4];
  #pragma unroll
  for (int t = 0; t < 4; ++t) acc[t] = (f32x4){0.f, 0.f, 0.f, 0.f};

  for (int k0 = 0; k0 < 512; k0 += 32) {
    short8 a = *(const short8*)(A + (size_t)(m0 + lo) * 512 + k0 + 8 * hi);
    #pragma unroll
    for (int t = 0; t < 4; ++t) {
      short8 b = *(const short8*)(W + (size_t)(n0 + 16 * t + lo) * 512 + k0 + 8 * hi);
      acc[t] = __builtin_amdgcn_mfma_f32_16x16x32_bf16(a, b, acc[t], 0, 0, 0);
    }
  }

  __shared__ __align__(16) unsigned short tile[64 * 64];
  bool isV = (z == 2 || z == 5);
  #pragma unroll
  for (int t = 0; t < 4; ++t) {
    #pragma unroll
    for (int r = 0; r < 4; ++r) {
      int row = wave * 16 + 4 * hi + r;
      int col = 16 * t + lo;
      unsigned short val = f2bf(acc[t][r]);
      if (isV) tile[col * 64 + row] = val;  // [dk][s_local]
      else     tile[row * 64 + col] = val;  // [s_local][dk]
    }
  }
  __syncthreads();

  int gm0 = blockIdx.x * 64;
  int b = gm0 >> 11;
  int s0 = gm0 & 2047;
  int h = blockIdx.y;
  unsigned short* dst = proj + PROJ_OFF[z];
  #pragma unroll
  for (int c = threadIdx.x; c < 512; c += 256) {
    int row = c >> 3, chunk = c & 7;
    uint4 data = *((uint4*)(tile + row * 64 + chunk * 8));
    size_t off;
    if (isV)
      off = ((size_t)(b * Hh + h) * 64 + row) * 2048 + s0 + chunk * 8;
    else
      off = ((size_t)(b * Hh + h) * 2048 + s0 + row) * 64 + chunk * 8;
    *((uint4*)(dst + off)) = data;
  }
}

// ---------------- 3. fused complex flash attention, split-K ----------------
// Fixed softmax shift m=0 (exact: scores are magnitudes >=0, bounded; softmax is
// shift-invariant). No per-iter cross-lane reduces at all; l reduced once at end.
// Split-K over ksh: each block does 2048>>ksh k-positions; partials are plain
// sums (no max to merge). 1D grid with XCD swizzle, consecutive logical blocks
// share a (bh,split) K/V slice.
__global__ __launch_bounds__(256) void ck_attn(
    const unsigned short* __restrict__ proj,
    const unsigned long long* __restrict__ mb,   // packed mask [B,S,32]
    unsigned short* __restrict__ xout,           // used when ksh==0
    float* __restrict__ opr, float* __restrict__ opp,  // [nsplit][BH][S][DK]
    float* __restrict__ lpart,                   // [nsplit][BH][S]
    int ksh)
{
  const unsigned short* qr  = proj;
  const unsigned short* kr  = proj + 2097152;
  const unsigned short* qp  = proj + 4194304;
  const unsigned short* kp  = proj + 6291456;
  const unsigned short* vrt = proj + 8388608;   // [B,H,DK,S]
  const unsigned short* vpt = proj + 10485760;

  int nsplit = 1 << ksh;
  int nb = 512 << ksh;
  int bid = blockIdx.x;
  int swz = (bid & 7) * (nb >> 3) + (bid >> 3);   // bijective XCD swizzle
  int qt = swz & 31;
  int g = swz >> 5;
  int split = g & (nsplit - 1);
  int bh = g >> ksh;
  int b = bh >> 3, h = bh & 7;

  int wave = threadIdx.x >> 6, lane = threadIdx.x & 63;
  int lo = lane & 15, hi = lane >> 4;
  size_t base = (size_t)bh * Ss * DKk;
  const unsigned short* Qr = qr + base;
  const unsigned short* Kr = kr + base;
  const unsigned short* Qp = qp + base;
  const unsigned short* Kp = kp + base;
  const unsigned short* Vr = vrt + base;
  const unsigned short* Vp = vpt + base;

  int q0 = qt * 64 + wave * 16;
  const unsigned long long* MBq = mb + ((size_t)b * Ss + q0) * 32;

  short8 fqr[2], fqp[2], fqpn[2];
  #pragma unroll
  for (int hf = 0; hf < 2; ++hf) {
    fqr[hf] = *(const short8*)(Qr + (size_t)(q0 + lo) * 64 + 32 * hf + 8 * hi);
    short8 p = *(const short8*)(Qp + (size_t)(q0 + lo) * 64 + 32 * hf + 8 * hi);
    fqp[hf] = p;
    union { short8 s; uint32_t u[4]; } pu; pu.s = p;
    #pragma unroll
    for (int i = 0; i < 4; ++i) pu.u[i] ^= 0x80008000u;
    fqpn[hf] = pu.s;
  }

  f32x4 o_r[4], o_p[4];
  float l_part[4];
  #pragma unroll
  for (int n = 0; n < 4; ++n) { o_r[n] = (f32x4){0,0,0,0}; o_p[n] = (f32x4){0,0,0,0}; }
  #pragma unroll
  for (int r = 0; r < 4; ++r) l_part[r] = 0.f;

  __shared__ __align__(16) unsigned short plds[4 * 1024];  // 2KB per wave, wave-private
  char* pbase = (char*)plds + wave * 2048;
  const float inv_scale = 0.08838834764831845f;            // 1/sqrt(2*DK)

  int klen = Ss >> ksh;
  int kbeg = split * klen;
  for (int k0 = kbeg; k0 < kbeg + klen; k0 += 64) {
    int wq = k0 >> 6;
    unsigned long long mrow[4];
    #pragma unroll
    for (int r = 0; r < 4; ++r) mrow[r] = MBq[(size_t)(4 * hi + r) * 32 + wq];
    unsigned long long andw = mrow[0] & mrow[1] & mrow[2] & mrow[3];
    bool need_mask = !__all((int)(andw == 0xFFFFFFFFFFFFFFFFull));

    // ---- scores: 4 col-tiles of 16, complex re/ph via 8 MFMAs each ----
    f32x4 sre[4], sph[4];
    #pragma unroll
    for (int t = 0; t < 4; ++t) {
      const unsigned short* krow = Kr + (size_t)(k0 + 16 * t + lo) * 64;
      const unsigned short* prow = Kp + (size_t)(k0 + 16 * t + lo) * 64;
      short8 bkr0 = *(const short8*)(krow + 8 * hi);
      short8 bkr1 = *(const short8*)(krow + 32 + 8 * hi);
      short8 bkp0 = *(const short8*)(prow + 8 * hi);
      short8 bkp1 = *(const short8*)(prow + 32 + 8 * hi);
      f32x4 re = (f32x4){0,0,0,0};
      re = __builtin_amdgcn_mfma_f32_16x16x32_bf16(fqr[0],  bkr0, re, 0,0,0);
      re = __builtin_amdgcn_mfma_f32_16x16x32_bf16(fqr[1],  bkr1, re, 0,0,0);
      re = __builtin_amdgcn_mfma_f32_16x16x32_bf16(fqpn[0], bkp0, re, 0,0,0);
      re = __builtin_amdgcn_mfma_f32_16x16x32_bf16(fqpn[1], bkp1, re, 0,0,0);
      f32x4 ph = (f32x4){0,0,0,0};
      ph = __builtin_amdgcn_mfma_f32_16x16x32_bf16(fqr[0],  bkp0, ph, 0,0,0);
      ph = __builtin_amdgcn_mfma_f32_16x16x32_bf16(fqr[1],  bkp1, ph, 0,0,0);
      ph = __builtin_amdgcn_mfma_f32_16x16x32_bf16(fqp[0],  bkr0, ph, 0,0,0);
      ph = __builtin_amdgcn_mfma_f32_16x16x32_bf16(fqp[1],  bkr1, ph, 0,0,0);
      sre[t] = re; sph[t] = ph;
    }

    // ---- magnitude + mask + exp (m=0); accumulate l per-lane, no shuffles ----
    float pvals[4][4];
    #pragma unroll
    for (int r = 0; r < 4; ++r) {
      unsigned long long sh = mrow[r] >> lo;
      #pragma unroll
      for (int t = 0; t < 4; ++t) {
        float re = sre[t][r], ph = sph[t][r];
        float v = __builtin_amdgcn_sqrtf(re * re + ph * ph) * inv_scale;
        if (need_mask)
          v = ((unsigned int)(sh >> (16 * t)) & 1u) ? v : -1e9f;
        float p = __expf(v);
        pvals[t][r] = p;
        l_part[r] += p;
      }
    }

    // ---- P -> bf16 -> LDS, XOR-swizzled; wave-private, no barrier ----
    #pragma unroll
    for (int t = 0; t < 4; ++t) {
      #pragma unroll
      for (int r = 0; r < 4; ++r) {
        int row = 4 * hi + r;
        int off = row * 128 + ((((16 * t + lo) * 2) ^ ((row & 7) << 4)));
        *(unsigned short*)(pbase + off) = f2bf(pvals[t][r]);
      }
    }

    // ---- PV ----
    short8 pa[2];
    #pragma unroll
    for (int hf = 0; hf < 2; ++hf) {
      int off = lo * 128 + (((hf * 64 + hi * 16)) ^ ((lo & 7) << 4));
      pa[hf] = *(const short8*)(pbase + off);
    }
    #pragma unroll
    for (int n = 0; n < 4; ++n) {
      const unsigned short* vr_row = Vr + (size_t)(16 * n + lo) * 2048 + k0;
      const unsigned short* vp_row = Vp + (size_t)(16 * n + lo) * 2048 + k0;
      short8 bvr0 = *(const short8*)(vr_row + 8 * hi);
      short8 bvr1 = *(const short8*)(vr_row + 32 + 8 * hi);
      short8 bvp0 = *(const short8*)(vp_row + 8 * hi);
      short8 bvp1 = *(const short8*)(vp_row + 32 + 8 * hi);
      o_r[n] = __builtin_amdgcn_mfma_f32_16x16x32_bf16(pa[0], bvr0, o_r[n], 0,0,0);
      o_r[n] = __builtin_amdgcn_mfma_f32_16x16x32_bf16(pa[1], bvr1, o_r[n], 0,0,0);
      o_p[n] = __builtin_amdgcn_mfma_f32_16x16x32_bf16(pa[0], bvp0, o_p[n], 0,0,0);
      o_p[n] = __builtin_amdgcn_mfma_f32_16x16x32_bf16(pa[1], bvp1, o_p[n], 0,0,0);
    }
  }

  // ---- epilogue: one 16-lane reduce of l, then store ----
  #pragma unroll
  for (int r = 0; r < 4; ++r) {
    float v = l_part[r];
    v += __shfl_xor(v, 1);
    v += __shfl_xor(v, 2);
    v += __shfl_xor(v, 4);
    v += __shfl_xor(v, 8);
    l_part[r] = v;
  }

  if (ksh == 0) {
    float invl[4];
    #pragma unroll
    for (int r = 0; r < 4; ++r) invl[r] = 1.f / l_part[r];
    #pragma unroll
    for (int n = 0; n < 4; ++n) {
      #pragma unroll
      for (int r = 0; r < 4; ++r) {
        int q = q0 + 4 * hi + r;
        size_t off = (size_t)(b * Ss + q) * Dd + h * 64 + 16 * n + lo;
        xout[off]         = f2bf(o_r[n][r] * invl[r]);
        xout[MAT_E + off] = f2bf(o_p[n][r] * invl[r]);
      }
    }
  } else {
    size_t obase = (size_t)(split * 16 + bh) * Ss;
    #pragma unroll
    for (int n = 0; n < 4; ++n) {
      #pragma unroll
      for (int r = 0; r < 4; ++r) {
        size_t off = (obase + q0 + 4 * hi + r) * 64 + 16 * n + lo;
        opr[off] = o_r[n][r];
        opp[off] = o_p[n][r];
      }
    }
    if (lo == 0)
      *(f32x4*)(lpart + obase + q0 + 4 * hi) =
          (f32x4){l_part[0], l_part[1], l_part[2], l_part[3]};
  }
}

// ---------------- 3b. split-K combine: out = sum(O_s) / sum(l_s) ----------
__global__ __launch_bounds__(256) void ck_attn_combine(
    const float* __restrict__ opr, const float* __restrict__ opp,
    const float* __restrict__ lpart,
    unsigned short* __restrict__ xout, int nsplit)
{
  int dkg = threadIdx.x & 15, qloc = threadIdx.x >> 4;
  int q = blockIdx.x * 16 + qloc;
  int bh = blockIdx.y;
  int b = bh >> 3, h = bh & 7;

  float l = 0.f;
  for (int s = 0; s < nsplit; ++s) l += lpart[(size_t)(s * 16 + bh) * Ss + q];
  float inv = 1.f / l;

  f32x4 ar = (f32x4){0,0,0,0}, ap = (f32x4){0,0,0,0};
  for (int s = 0; s < nsplit; ++s) {
    size_t off = ((size_t)(s * 16 + bh) * Ss + q) * 64 + dkg * 4;
    ar += *(const f32x4*)(opr + off);
    ap += *(const f32x4*)(opp + off);
  }
  size_t ob = ((size_t)b * Ss + q) * Dd + h * 64 + dkg * 4;
  unsigned short o0[4], o1[4];
  #pragma unroll
  for (int j = 0; j < 4; ++j) { o0[j] = f2bf(ar[j] * inv); o1[j] = f2bf(ap[j] * inv); }
  *(uint2*)(xout + ob)         = *(uint2*)o0;
  *(uint2*)(xout + MAT_E + ob) = *(uint2*)o1;
}

// ---------------- 4. output projection -> fp32 d_out ----------------
__global__ __launch_bounds__(256) void ck_out_gemm(
    const unsigned short* __restrict__ x,    // xr@0, xp@MAT_E bf16 [4096,512]
    const unsigned short* __restrict__ wot,  // w_o transposed bf16 [512,512]
    float* __restrict__ out)
{
  int z = blockIdx.z;
  const unsigned short* A = x + (size_t)z * MAT_E;
  float* O = out + (size_t)z * MAT_E;

  int wave = threadIdx.x >> 6, lane = threadIdx.x & 63;
  int lo = lane & 15, hi = lane >> 4;
  int m0 = blockIdx.x * 64 + wave * 16;
  int n0 = blockIdx.y * 64;

  f32x4 acc[4];
  #pragma unroll
  for (int t = 0; t < 4; ++t) acc[t] = (f32x4){0.f, 0.f, 0.f, 0.f};

  for (int k0 = 0; k0 < 512; k0 += 32) {
    short8 a = *(const short8*)(A + (size_t)(m0 + lo) * 512 + k0 + 8 * hi);
    #pragma unroll
    for (int t = 0; t < 4; ++t) {
      short8 b = *(const short8*)(wot + (size_t)(n0 + 16 * t + lo) * 512 + k0 + 8 * hi);
      acc[t] = __builtin_amdgcn_mfma_f32_16x16x32_bf16(a, b, acc[t], 0, 0, 0);
    }
  }
  #pragma unroll
  for (int t = 0; t < 4; ++t) {
    #pragma unroll
    for (int r = 0; r < 4; ++r) {
      int m = m0 + 4 * hi + r;
      int n = n0 + 16 * t + lo;
      O[(size_t)m * 512 + n] = acc[t][r];
    }
  }
}

// ---------------- launch ----------------
extern "C" void kernel_launch(void* const* d_in, const int* in_sizes, int n_in,
                              void* d_out, int out_size, void* d_ws, size_t ws_size,
                              hipStream_t stream) {
  const float* q_real  = (const float*)d_in[0];
  const float* k_real  = (const float*)d_in[1];
  const float* v_real  = (const float*)d_in[2];
  const float* q_phase = (const float*)d_in[3];
  const float* k_phase = (const float*)d_in[4];
  const float* v_phase = (const float*)d_in[5];
  const float* w_q     = (const float*)d_in[6];
  const float* w_k     = (const float*)d_in[7];
  const float* w_v     = (const float*)d_in[8];
  const float* w_o     = (const float*)d_in[9];
  const int*   mask    = (const int*)d_in[10];
  float* out = (float*)d_out;

  unsigned short* ws   = (unsigned short*)d_ws;
  unsigned short* XB   = ws;                            // 6*MAT_E bf16 (dead after proj)
  unsigned short* WT   = ws + 6 * (size_t)MAT_E;        // 4*W_E
  unsigned short* PROJ = WT + 4 * (size_t)W_E;          // 6*MAT_E
  unsigned short* XOUT = PROJ + 6 * (size_t)MAT_E;      // 2*MAT_E
  unsigned long long* MB = (unsigned long long*)XB;     // 1 MB, aliases dead XB

  // split-K partials appended after XOUT: per split 2*2,097,152 f32 (O) + 32K f32 (l)
  const size_t BASE_E  = 6 * (size_t)MAT_E + 4 * (size_t)W_E + 6 * (size_t)MAT_E + 2 * (size_t)MAT_E;
  const size_t BASE_B  = BASE_E * 2;                    // 60,817,408 bytes
  const size_t PER_SPLIT_B = 2ull * 2097152ull * 4ull + 16ull * 2048ull * 4ull;  // 16,908,288

  int ksh = 0;                                          // deterministic: ws_size is fixed
  if      (ws_size >= BASE_B + 4 * PER_SPLIT_B) ksh = 2;
  else if (ws_size >= BASE_B + 2 * PER_SPLIT_B) ksh = 1;
  int nsplit = 1 << ksh;

  float* OPr = (float*)(ws + BASE_E);
  float* OPp = OPr + (size_t)nsplit * 2097152;
  float* LP  = OPp + (size_t)nsplit * 2097152;

  ck_cvt_in  <<<dim3(2048, 6), 256, 0, stream>>>(q_real, k_real, v_real,
                                                 q_phase, k_phase, v_phase, XB);
  ck_cvt_wt  <<<dim3(1024, 4), 256, 0, stream>>>(w_q, w_k, w_v, w_o, WT);
  ck_proj_gemm<<<dim3(64, 8, 6), 256, 0, stream>>>(XB, WT, PROJ);
  ck_mask_pack<<<dim3(32768), 256, 0, stream>>>(mask, MB);   // after proj: XB dead
  ck_attn    <<<dim3(512 << ksh), 256, 0, stream>>>(PROJ, MB, XOUT, OPr, OPp, LP, ksh);
  if (nsplit > 1)
    ck_attn_combine<<<dim3(128, 16), 256, 0, stream>>>(OPr, OPp, LP, XOUT, nsplit);
  ck_out_gemm<<<dim3(64, 8, 2), 256, 0, stream>>>(XOUT, WT + 3 * (size_t)W_E, out);
}

// Round 5
// 381.061 us; speedup vs baseline: 1.4475x; 1.4475x over previous
//
#include <hip/hip_runtime.h>
#include <hip/hip_bf16.h>
#include <stdint.h>

// Complex-valued MHA: B=2, S=2048, D=512, H=8, DK=64
#define Bb 2
#define Ss 2048
#define Dd 512
#define Hh 8
#define DKk 64

#define NROW 4096            // B*S
#define MAT_E 2097152        // B*S*D
#define W_E 262144           // D*D

typedef __attribute__((ext_vector_type(8))) short short8;
typedef __attribute__((ext_vector_type(4))) float f32x4;

__device__ __forceinline__ unsigned short f2bf(float f) {
  union { float f; uint32_t u; } v; v.f = f;
  uint32_t u = v.u;
  uint32_t r = u + 0x7FFFu + ((u >> 16) & 1u);
  return (unsigned short)(r >> 16);
}

// async global->LDS, 16B per lane; LDS dest = wave-uniform base + lane*16
__device__ __forceinline__ void g2l16(const char* g, char* l) {
  __builtin_amdgcn_global_load_lds(
      (const __attribute__((address_space(1))) void*)g,
      (__attribute__((address_space(3))) void*)l, 16, 0, 0);
}

// ---------------- 1a. convert activations fp32 -> bf16 ----------------
__global__ __launch_bounds__(256) void ck_cvt_in(
    const float* __restrict__ a0, const float* __restrict__ a1,
    const float* __restrict__ a2, const float* __restrict__ a3,
    const float* __restrict__ a4, const float* __restrict__ a5,
    unsigned short* __restrict__ out)
{
  int z = blockIdx.y;
  const float* src = z==0?a0: z==1?a1: z==2?a2: z==3?a3: z==4?a4: a5;
  unsigned short* dst = out + (size_t)z * MAT_E;
  int i = blockIdx.x * 256 + threadIdx.x;
  float4 v = ((const float4*)src)[i];
  unsigned short o[4] = {f2bf(v.x), f2bf(v.y), f2bf(v.z), f2bf(v.w)};
  *((uint2*)(dst + (size_t)i * 4)) = *((uint2*)o);
}

// ---------------- 1b. convert + transpose weights: Wt[d][k] = w[k][d] ----
__global__ __launch_bounds__(256) void ck_cvt_wt(
    const float* __restrict__ w0, const float* __restrict__ w1,
    const float* __restrict__ w2, const float* __restrict__ w3,
    unsigned short* __restrict__ out)
{
  int z = blockIdx.y;
  const float* w = z==0?w0: z==1?w1: z==2?w2: w3;
  unsigned short* wt = out + (size_t)z * W_E;
  int t = blockIdx.x * 256 + threadIdx.x;
  int d = t >> 9, k = t & 511;
  wt[t] = f2bf(w[k * 512 + d]);
}

// ---------------- 1c. pack mask int32 -> 64-bit words ----------------
__global__ __launch_bounds__(256) void ck_mask_pack(
    const int* __restrict__ mask, unsigned long long* __restrict__ mb)
{
  size_t i = (size_t)blockIdx.x * 256 + threadIdx.x;
  int v = mask[i];
  unsigned long long bits = __ballot(v != 0);
  if ((threadIdx.x & 63) == 0) mb[i >> 6] = bits;
}

// ---------------- 2. projection GEMM ----------------
__device__ const size_t PROJ_OFF[6] = {0, 2097152, 8388608, 4194304, 6291456, 10485760};

__global__ __launch_bounds__(256) void ck_proj_gemm(
    const unsigned short* __restrict__ xb,
    const unsigned short* __restrict__ wt,
    unsigned short* __restrict__ proj)
{
  int z = blockIdx.z;
  int wsel = z % 3;
  const unsigned short* A = xb + (size_t)z * MAT_E;
  const unsigned short* W = wt + (size_t)wsel * W_E;

  int wave = threadIdx.x >> 6, lane = threadIdx.x & 63;
  int lo = lane & 15, hi = lane >> 4;
  int m0 = blockIdx.x * 64 + wave * 16;
  int n0 = blockIdx.y * 64;

  f32x4 acc[4];
  #pragma unroll
  for (int t = 0; t < 4; ++t) acc[t] = (f32x4){0.f, 0.f, 0.f, 0.f};

  #pragma unroll 2
  for (int k0 = 0; k0 < 512; k0 += 32) {
    short8 a = *(const short8*)(A + (size_t)(m0 + lo) * 512 + k0 + 8 * hi);
    #pragma unroll
    for (int t = 0; t < 4; ++t) {
      short8 b = *(const short8*)(W + (size_t)(n0 + 16 * t + lo) * 512 + k0 + 8 * hi);
      acc[t] = __builtin_amdgcn_mfma_f32_16x16x32_bf16(a, b, acc[t], 0, 0, 0);
    }
  }

  __shared__ __align__(16) unsigned short tile[64 * 64];
  bool isV = (z == 2 || z == 5);
  #pragma unroll
  for (int t = 0; t < 4; ++t) {
    #pragma unroll
    for (int r = 0; r < 4; ++r) {
      int row = wave * 16 + 4 * hi + r;
      int col = 16 * t + lo;
      unsigned short val = f2bf(acc[t][r]);
      if (isV) tile[col * 64 + row] = val;  // [dk][s_local]
      else     tile[row * 64 + col] = val;  // [s_local][dk]
    }
  }
  __syncthreads();

  int gm0 = blockIdx.x * 64;
  int b = gm0 >> 11;
  int s0 = gm0 & 2047;
  int h = blockIdx.y;
  unsigned short* dst = proj + PROJ_OFF[z];
  #pragma unroll
  for (int c = threadIdx.x; c < 512; c += 256) {
    int row = c >> 3, chunk = c & 7;
    uint4 data = *((uint4*)(tile + row * 64 + chunk * 8));
    size_t off;
    if (isV)
      off = ((size_t)(b * Hh + h) * 64 + row) * 2048 + s0 + chunk * 8;
    else
      off = ((size_t)(b * Hh + h) * 2048 + s0 + row) * 64 + chunk * 8;
    *((uint4*)(dst + off)) = data;
  }
}

// ---------------- 3. fused complex flash attention, LDS-staged ----------
// K/V tiles staged via global_load_lds (no VGPR round-trip -> memory
// parallelism without register pressure). XOR swizzle done by pre-swizzling
// the per-lane GLOBAL source (LDS dest is linear, rule #21) and applying the
// same XOR on reads. Kr/Kp double-buffered (prefetch k0+64 during scores);
// Vr/Vp single-buffered (staged at iter start, consumed after barrier A).
__global__ __launch_bounds__(256) void ck_attn(
    const unsigned short* __restrict__ proj,
    const unsigned long long* __restrict__ mb,
    unsigned short* __restrict__ xout)
{
  const unsigned short* qr  = proj;
  const unsigned short* kr  = proj + 2097152;
  const unsigned short* qp  = proj + 4194304;
  const unsigned short* kp  = proj + 6291456;
  const unsigned short* vrt = proj + 8388608;   // [B,H,DK,S]
  const unsigned short* vpt = proj + 10485760;

  int bid = blockIdx.x;
  int swz = (bid & 7) * 64 + (bid >> 3);     // bijective XCD swizzle (512%8==0)
  int qt = swz & 31, h = (swz >> 5) & 7, b = swz >> 8;

  int wave = threadIdx.x >> 6, lane = threadIdx.x & 63;
  int lo = lane & 15, hi = lane >> 4;
  int bh = b * Hh + h;
  size_t base = (size_t)bh * Ss * DKk;
  const char* Krb = (const char*)(kr + base);
  const char* Kpb = (const char*)(kp + base);
  const char* Vrb = (const char*)(vrt + base);
  const char* Vpb = (const char*)(vpt + base);
  const unsigned short* Qr = qr + base;
  const unsigned short* Qp = qp + base;

  // LDS: K dbuf 2x2x8KB + V 2x8KB + P 8KB = 56KB
  __shared__ __align__(16) char kbuf[2][2][8192];
  __shared__ __align__(16) char vbuf[2][8192];
  __shared__ __align__(16) unsigned short plds[4 * 1024];
  char* pbase = (char*)plds + wave * 2048;

  // staging geometry: LDS linear slot (j*4096 + wave*1024 + lane*16)
  //  -> row = j*32 + wave*8 + (lane>>3), colbyte = (lane&7)*16
  // source column pre-swizzled: scol = colbyte ^ ((row&7)<<4)
  int srow = wave * 8 + (lane >> 3);                       // j=0 row
  int scol = 16 * ((lane & 7) ^ ((lane >> 3) & 7));
  int lslot = wave * 1024 + lane * 16;

  #define STAGE_T(gbase, rstrideB, ltile)                                    \
    {                                                                        \
      g2l16((gbase) + (size_t)(srow) * (rstrideB) + scol, (ltile) + lslot);  \
      g2l16((gbase) + (size_t)(srow + 32) * (rstrideB) + scol,               \
            (ltile) + 4096 + lslot);                                         \
    }

  int q0 = qt * 64 + wave * 16;
  const unsigned long long* MBq = mb + ((size_t)b * Ss + q0) * 32;

  // Q fragments in registers for the whole kernel; fqpn = -qp (sign flip)
  short8 fqr[2], fqp[2], fqpn[2];
  #pragma unroll
  for (int hf = 0; hf < 2; ++hf) {
    fqr[hf] = *(const short8*)(Qr + (size_t)(q0 + lo) * 64 + 32 * hf + 8 * hi);
    short8 p = *(const short8*)(Qp + (size_t)(q0 + lo) * 64 + 32 * hf + 8 * hi);
    fqp[hf] = p;
    union { short8 s; uint32_t u[4]; } pu; pu.s = p;
    #pragma unroll
    for (int i = 0; i < 4; ++i) pu.u[i] ^= 0x80008000u;
    fqpn[hf] = pu.s;
  }

  f32x4 o_r[4], o_p[4];
  float l_part[4];
  #pragma unroll
  for (int n = 0; n < 4; ++n) { o_r[n] = (f32x4){0,0,0,0}; o_p[n] = (f32x4){0,0,0,0}; }
  #pragma unroll
  for (int r = 0; r < 4; ++r) l_part[r] = 0.f;

  const float inv_scale = 0.08838834764831845f;  // 1/sqrt(2*DK)

  // prologue: stage K[0]
  STAGE_T(Krb, 128, kbuf[0][0]);
  STAGE_T(Kpb, 128, kbuf[0][1]);
  __syncthreads();

  int c = 0;
  for (int k0 = 0; k0 < Ss; k0 += 64) {
    // issue V[t] and prefetch K[t+1] (async; drained by barrier A)
    STAGE_T(Vrb + (size_t)k0 * 2, 4096, vbuf[0]);
    STAGE_T(Vpb + (size_t)k0 * 2, 4096, vbuf[1]);
    if (k0 + 64 < Ss) {
      STAGE_T(Krb + (size_t)(k0 + 64) * 128, 128, kbuf[c ^ 1][0]);
      STAGE_T(Kpb + (size_t)(k0 + 64) * 128, 128, kbuf[c ^ 1][1]);
    }

    int wq = k0 >> 6;
    unsigned long long mrow[4];
    #pragma unroll
    for (int r = 0; r < 4; ++r) mrow[r] = MBq[(size_t)(4 * hi + r) * 32 + wq];
    unsigned long long andw = mrow[0] & mrow[1] & mrow[2] & mrow[3];
    bool need_mask = !__all((int)(andw == 0xFFFFFFFFFFFFFFFFull));

    // ---- scores from K LDS tiles (swizzled reads, conflict-free) ----
    const char* Kl = kbuf[c][0];
    const char* Pl = kbuf[c][1];
    f32x4 sre[4], sph[4];
    #pragma unroll
    for (int t = 0; t < 4; ++t) {
      int r0 = 16 * t + lo;
      int sw = (lo & 7) << 4;
      short8 bkr0 = *(const short8*)(Kl + r0 * 128 + ((16 * hi) ^ sw));
      short8 bkr1 = *(const short8*)(Kl + r0 * 128 + ((64 + 16 * hi) ^ sw));
      short8 bkp0 = *(const short8*)(Pl + r0 * 128 + ((16 * hi) ^ sw));
      short8 bkp1 = *(const short8*)(Pl + r0 * 128 + ((64 + 16 * hi) ^ sw));
      f32x4 re = (f32x4){0,0,0,0};
      re = __builtin_amdgcn_mfma_f32_16x16x32_bf16(fqr[0],  bkr0, re, 0,0,0);
      re = __builtin_amdgcn_mfma_f32_16x16x32_bf16(fqr[1],  bkr1, re, 0,0,0);
      re = __builtin_amdgcn_mfma_f32_16x16x32_bf16(fqpn[0], bkp0, re, 0,0,0);
      re = __builtin_amdgcn_mfma_f32_16x16x32_bf16(fqpn[1], bkp1, re, 0,0,0);
      f32x4 ph = (f32x4){0,0,0,0};
      ph = __builtin_amdgcn_mfma_f32_16x16x32_bf16(fqr[0],  bkp0, ph, 0,0,0);
      ph = __builtin_amdgcn_mfma_f32_16x16x32_bf16(fqr[1],  bkp1, ph, 0,0,0);
      ph = __builtin_amdgcn_mfma_f32_16x16x32_bf16(fqp[0],  bkr0, ph, 0,0,0);
      ph = __builtin_amdgcn_mfma_f32_16x16x32_bf16(fqp[1],  bkr1, ph, 0,0,0);
      sre[t] = re; sph[t] = ph;
    }

    // ---- magnitude + mask + exp (fixed shift m=0, exact) ----
    float pvals[4][4];
    #pragma unroll
    for (int r = 0; r < 4; ++r) {
      unsigned long long sh = mrow[r] >> lo;
      #pragma unroll
      for (int t = 0; t < 4; ++t) {
        float re = sre[t][r], ph = sph[t][r];
        float v = __builtin_amdgcn_sqrtf(re * re + ph * ph) * inv_scale;
        if (need_mask)
          v = ((unsigned int)(sh >> (16 * t)) & 1u) ? v : -1e9f;
        float p = __expf(v);
        pvals[t][r] = p;
        l_part[r] += p;
      }
    }

    // ---- P -> bf16 -> wave-private LDS (XOR-swizzled) ----
    #pragma unroll
    for (int t = 0; t < 4; ++t) {
      #pragma unroll
      for (int r = 0; r < 4; ++r) {
        int row = 4 * hi + r;
        int off = row * 128 + ((((16 * t + lo) * 2) ^ ((row & 7) << 4)));
        *(unsigned short*)(pbase + off) = f2bf(pvals[t][r]);
      }
    }

    __syncthreads();   // barrier A: drains vmcnt -> V[t], K[t+1] landed

    // ---- PV from V LDS tiles ----
    short8 pa[2];
    #pragma unroll
    for (int hf = 0; hf < 2; ++hf) {
      int off = lo * 128 + (((hf * 64 + hi * 16)) ^ ((lo & 7) << 4));
      pa[hf] = *(const short8*)(pbase + off);
    }
    #pragma unroll
    for (int n = 0; n < 4; ++n) {
      int r0 = 16 * n + lo;
      int sw = (lo & 7) << 4;
      short8 bvr0 = *(const short8*)(vbuf[0] + r0 * 128 + ((16 * hi) ^ sw));
      short8 bvr1 = *(const short8*)(vbuf[0] + r0 * 128 + ((64 + 16 * hi) ^ sw));
      short8 bvp0 = *(const short8*)(vbuf[1] + r0 * 128 + ((16 * hi) ^ sw));
      short8 bvp1 = *(const short8*)(vbuf[1] + r0 * 128 + ((64 + 16 * hi) ^ sw));
      o_r[n] = __builtin_amdgcn_mfma_f32_16x16x32_bf16(pa[0], bvr0, o_r[n], 0,0,0);
      o_r[n] = __builtin_amdgcn_mfma_f32_16x16x32_bf16(pa[1], bvr1, o_r[n], 0,0,0);
      o_p[n] = __builtin_amdgcn_mfma_f32_16x16x32_bf16(pa[0], bvp0, o_p[n], 0,0,0);
      o_p[n] = __builtin_amdgcn_mfma_f32_16x16x32_bf16(pa[1], bvp1, o_p[n], 0,0,0);
    }

    __syncthreads();   // barrier B: all waves done with vbuf before next stage
    c ^= 1;
  }

  // ---- epilogue: reduce l across 16-lane groups, normalize, store ----
  #pragma unroll
  for (int r = 0; r < 4; ++r) {
    float v = l_part[r];
    v += __shfl_xor(v, 1);
    v += __shfl_xor(v, 2);
    v += __shfl_xor(v, 4);
    v += __shfl_xor(v, 8);
    l_part[r] = v;
  }
  float invl[4];
  #pragma unroll
  for (int r = 0; r < 4; ++r) invl[r] = 1.f / l_part[r];
  #pragma unroll
  for (int n = 0; n < 4; ++n) {
    #pragma unroll
    for (int r = 0; r < 4; ++r) {
      int q = q0 + 4 * hi + r;
      size_t off = (size_t)(b * Ss + q) * Dd + h * 64 + 16 * n + lo;
      xout[off]         = f2bf(o_r[n][r] * invl[r]);
      xout[MAT_E + off] = f2bf(o_p[n][r] * invl[r]);
    }
  }
  #undef STAGE_T
}

// ---------------- 4. output projection -> fp32 d_out ----------------
__global__ __launch_bounds__(256) void ck_out_gemm(
    const unsigned short* __restrict__ x,
    const unsigned short* __restrict__ wot,
    float* __restrict__ out)
{
  int z = blockIdx.z;
  const unsigned short* A = x + (size_t)z * MAT_E;
  float* O = out + (size_t)z * MAT_E;

  int wave = threadIdx.x >> 6, lane = threadIdx.x & 63;
  int lo = lane & 15, hi = lane >> 4;
  int m0 = blockIdx.x * 64 + wave * 16;
  int n0 = blockIdx.y * 64;

  f32x4 acc[4];
  #pragma unroll
  for (int t = 0; t < 4; ++t) acc[t] = (f32x4){0.f, 0.f, 0.f, 0.f};

  #pragma unroll 2
  for (int k0 = 0; k0 < 512; k0 += 32) {
    short8 a = *(const short8*)(A + (size_t)(m0 + lo) * 512 + k0 + 8 * hi);
    #pragma unroll
    for (int t = 0; t < 4; ++t) {
      short8 b = *(const short8*)(wot + (size_t)(n0 + 16 * t + lo) * 512 + k0 + 8 * hi);
      acc[t] = __builtin_amdgcn_mfma_f32_16x16x32_bf16(a, b, acc[t], 0, 0, 0);
    }
  }
  #pragma unroll
  for (int t = 0; t < 4; ++t) {
    #pragma unroll
    for (int r = 0; r < 4; ++r) {
      int m = m0 + 4 * hi + r;
      int n = n0 + 16 * t + lo;
      O[(size_t)m * 512 + n] = acc[t][r];
    }
  }
}

// ---------------- launch ----------------
extern "C" void kernel_launch(void* const* d_in, const int* in_sizes, int n_in,
                              void* d_out, int out_size, void* d_ws, size_t ws_size,
                              hipStream_t stream) {
  const float* q_real  = (const float*)d_in[0];
  const float* k_real  = (const float*)d_in[1];
  const float* v_real  = (const float*)d_in[2];
  const float* q_phase = (const float*)d_in[3];
  const float* k_phase = (const float*)d_in[4];
  const float* v_phase = (const float*)d_in[5];
  const float* w_q     = (const float*)d_in[6];
  const float* w_k     = (const float*)d_in[7];
  const float* w_v     = (const float*)d_in[8];
  const float* w_o     = (const float*)d_in[9];
  const int*   mask    = (const int*)d_in[10];
  float* out = (float*)d_out;

  unsigned short* ws   = (unsigned short*)d_ws;
  unsigned short* XB   = ws;                            // 6*MAT_E bf16 (dead after proj)
  unsigned short* WT   = ws + 6 * (size_t)MAT_E;        // 4*W_E
  unsigned short* PROJ = WT + 4 * (size_t)W_E;          // 6*MAT_E
  unsigned short* XOUT = PROJ + 6 * (size_t)MAT_E;      // 2*MAT_E
  unsigned long long* MB = (unsigned long long*)XB;     // aliases dead XB

  ck_cvt_in  <<<dim3(2048, 6), 256, 0, stream>>>(q_real, k_real, v_real,
                                                 q_phase, k_phase, v_phase, XB);
  ck_cvt_wt  <<<dim3(1024, 4), 256, 0, stream>>>(w_q, w_k, w_v, w_o, WT);
  ck_proj_gemm<<<dim3(64, 8, 6), 256, 0, stream>>>(XB, WT, PROJ);
  ck_mask_pack<<<dim3(32768), 256, 0, stream>>>(mask, MB);
  ck_attn    <<<dim3(512), 256, 0, stream>>>(PROJ, MB, XOUT);
  ck_out_gemm<<<dim3(64, 8, 2), 256, 0, stream>>>(XOUT, WT + 3 * (size_t)W_E, out);
}

// Round 7
// 263.523 us; speedup vs baseline: 2.0931x; 1.4460x over previous
//
#include <hip/hip_runtime.h>
#include <hip/hip_bf16.h>
#include <stdint.h>

// Complex-valued MHA: B=2, S=2048, D=512, H=8, DK=64
#define Bb 2
#define Ss 2048
#define Dd 512
#define Hh 8
#define DKk 64

#define NROW 4096            // B*S
#define MAT_E 2097152        // B*S*D
#define W_E 262144           // D*D

typedef __attribute__((ext_vector_type(8))) short short8;
typedef __attribute__((ext_vector_type(4))) float f32x4;

__device__ __forceinline__ unsigned short f2bf(float f) {
  union { float f; uint32_t u; } v; v.f = f;
  uint32_t u = v.u;
  uint32_t r = u + 0x7FFFu + ((u >> 16) & 1u);
  return (unsigned short)(r >> 16);
}

// async global->LDS, 16B/lane; LDS dest = wave-uniform base + lane*16
__device__ __forceinline__ void g2l16(const char* g, char* l) {
  __builtin_amdgcn_global_load_lds(
      (const __attribute__((address_space(1))) void*)g,
      (__attribute__((address_space(3))) void*)l, 16, 0, 0);
}

// ---------------- 1a. convert activations fp32 -> bf16 ----------------
__global__ __launch_bounds__(256) void ck_cvt_in(
    const float* __restrict__ a0, const float* __restrict__ a1,
    const float* __restrict__ a2, const float* __restrict__ a3,
    const float* __restrict__ a4, const float* __restrict__ a5,
    unsigned short* __restrict__ out)
{
  int z = blockIdx.y;
  const float* src = z==0?a0: z==1?a1: z==2?a2: z==3?a3: z==4?a4: a5;
  unsigned short* dst = out + (size_t)z * MAT_E;
  int i = blockIdx.x * 256 + threadIdx.x;
  float4 v = ((const float4*)src)[i];
  unsigned short o[4] = {f2bf(v.x), f2bf(v.y), f2bf(v.z), f2bf(v.w)};
  *((uint2*)(dst + (size_t)i * 4)) = *((uint2*)o);
}

// ---------------- 1b. convert + transpose weights: Wt[d][k] = w[k][d] ----
__global__ __launch_bounds__(256) void ck_cvt_wt(
    const float* __restrict__ w0, const float* __restrict__ w1,
    const float* __restrict__ w2, const float* __restrict__ w3,
    unsigned short* __restrict__ out)
{
  int z = blockIdx.y;
  const float* w = z==0?w0: z==1?w1: z==2?w2: w3;
  unsigned short* wt = out + (size_t)z * W_E;
  int t = blockIdx.x * 256 + threadIdx.x;
  int d = t >> 9, k = t & 511;
  wt[t] = f2bf(w[k * 512 + d]);
}

// ---------------- 1c. pack mask int32 -> 64-bit words ----------------
__global__ __launch_bounds__(256) void ck_mask_pack(
    const int* __restrict__ mask, unsigned long long* __restrict__ mb)
{
  size_t i = (size_t)blockIdx.x * 256 + threadIdx.x;
  int v = mask[i];
  unsigned long long bits = __ballot(v != 0);
  if ((threadIdx.x & 63) == 0) mb[i >> 6] = bits;
}

// ---------------- 2. projection GEMM, m97 structure ----------------
// 128x128 tile, 4 waves (64x64 quadrant each, 4x4 frags), BK=32,
// global_load_lds dbuf staging. z: 0=qr 1=kr 2=vr(T) 3=qp 4=kp 5=vp(T).
__device__ const size_t PROJ_OFF[6] = {0, 2097152, 8388608, 4194304, 6291456, 10485760};

__global__ __launch_bounds__(256) void ck_proj_gemm(
    const unsigned short* __restrict__ xb,
    const unsigned short* __restrict__ wt,
    unsigned short* __restrict__ proj)
{
  int z = blockIdx.z;
  const char* A = (const char*)(xb + (size_t)z * MAT_E);
  const char* W = (const char*)(wt + (size_t)(z % 3) * W_E);

  int tid = threadIdx.x;
  int wave = tid >> 6, lane = tid & 63;
  int lo = lane & 15, hi = lane >> 4;
  int wr = wave >> 1, wc = wave & 1;
  int m0 = blockIdx.x * 128, n0 = blockIdx.y * 128;

  // staging 4x8KB (A dbuf + B dbuf) = 32KB; epilogue tile 128x136x2B = 34816B
  __shared__ __align__(16) char smem[34816];
  char* A0 = smem;          char* A1 = smem + 8192;
  char* B0 = smem + 16384;  char* B1 = smem + 24576;

  // staging: chunk c = j*256 + tid: row=c>>2, slot=c&3; global kchunk
  // inverse-swizzled (rule #21): src slot = slot ^ ((row>>1)&3)
  int r0s = tid >> 2,        s0s = (tid & 3) ^ ((r0s >> 1) & 3);
  int c1  = 256 + tid;
  int r1s = c1 >> 2,         s1s = (c1 & 3) ^ ((r1s >> 1) & 3);
  int lb0 = wave * 1024;          // LDS base, call j=0 (wave-uniform)
  int lb1 = 4096 + wave * 1024;   // call j=1

  auto stage = [&](char* Ax, char* Bx, int k0) {
    g2l16(A + (size_t)(m0 + r0s) * 1024 + k0 * 2 + s0s * 16, Ax + lb0);
    g2l16(A + (size_t)(m0 + r1s) * 1024 + k0 * 2 + s1s * 16, Ax + lb1);
    g2l16(W + (size_t)(n0 + r0s) * 1024 + k0 * 2 + s0s * 16, Bx + lb0);
    g2l16(W + (size_t)(n0 + r1s) * 1024 + k0 * 2 + s1s * 16, Bx + lb1);
  };

  f32x4 acc[4][4];
  #pragma unroll
  for (int mf = 0; mf < 4; ++mf)
    #pragma unroll
    for (int nf = 0; nf < 4; ++nf) acc[mf][nf] = (f32x4){0.f, 0.f, 0.f, 0.f};

  int swz = (hi ^ ((lo >> 1) & 3)) * 16;   // read-side XOR (row>>1)&3 == (lo>>1)&3

  auto compute = [&](const char* Ax, const char* Bx) {
    short8 af[4], bf[4];
    #pragma unroll
    for (int mf = 0; mf < 4; ++mf)
      af[mf] = *(const short8*)(Ax + (wr * 64 + mf * 16 + lo) * 64 + swz);
    #pragma unroll
    for (int nf = 0; nf < 4; ++nf)
      bf[nf] = *(const short8*)(Bx + (wc * 64 + nf * 16 + lo) * 64 + swz);
    #pragma unroll
    for (int mf = 0; mf < 4; ++mf)
      #pragma unroll
      for (int nf = 0; nf < 4; ++nf)
        acc[mf][nf] = __builtin_amdgcn_mfma_f32_16x16x32_bf16(af[mf], bf[nf], acc[mf][nf], 0, 0, 0);
  };

  stage(A0, B0, 0);
  __syncthreads();
  #pragma unroll 1
  for (int s = 0; s < 16; s += 2) {
    stage(A1, B1, (s + 1) * 32);          // s+1 <= 15 always
    compute(A0, B0);
    __syncthreads();
    if (s + 2 < 16) stage(A0, B0, (s + 2) * 32);
    compute(A1, B1);
    __syncthreads();
  }

  // epilogue through pad-136 LDS tile (16B-aligned rows, <=2-way banks)
  unsigned short* ep = (unsigned short*)smem;
  bool isV = (z == 2 || z == 5);
  #pragma unroll
  for (int mf = 0; mf < 4; ++mf)
    #pragma unroll
    for (int nf = 0; nf < 4; ++nf)
      #pragma unroll
      for (int r = 0; r < 4; ++r) {
        int grow = wr * 64 + mf * 16 + 4 * hi + r;
        int gcol = wc * 64 + nf * 16 + lo;
        unsigned short v = f2bf(acc[mf][nf][r]);
        if (isV) ep[gcol * 136 + grow] = v;   // transposed [dk-local][s-local]
        else     ep[grow * 136 + gcol] = v;   // [s-local][col-local]
      }
  __syncthreads();

  int b  = blockIdx.x >> 4;
  int s0 = (blockIdx.x * 128) & 2047;
  int h0 = blockIdx.y * 2;                    // 128 cols = 2 heads
  unsigned short* dst = proj + PROJ_OFF[z];
  #pragma unroll
  for (int i = 0; i < 8; ++i) {
    int cc = i * 256 + tid;
    int rr = cc >> 4, ch = cc & 15;
    uint4 d = *(const uint4*)(ep + rr * 136 + ch * 8);
    size_t off;
    if (isV)   // rr = local dk-col, ch indexes s-chunks: Vt[b,h,dk,s]
      off = ((size_t)(b * 8 + h0 + (rr >> 6)) * 64 + (rr & 63)) * 2048 + s0 + ch * 8;
    else       // rr = local s-row, ch indexes cols: [b,h,s,dk]
      off = ((size_t)(b * 8 + h0 + (ch >> 3)) * 2048 + s0 + rr) * 64 + (ch & 7) * 8;
    *(uint4*)(dst + off) = d;
  }
}

// ---------------- 3. fused complex flash attention, LDS-staged ----------
__global__ __launch_bounds__(256) void ck_attn(
    const unsigned short* __restrict__ proj,
    const unsigned long long* __restrict__ mb,
    unsigned short* __restrict__ xout)
{
  const unsigned short* qr  = proj;
  const unsigned short* kr  = proj + 2097152;
  const unsigned short* qp  = proj + 4194304;
  const unsigned short* kp  = proj + 6291456;
  const unsigned short* vrt = proj + 8388608;   // [B,H,DK,S]
  const unsigned short* vpt = proj + 10485760;

  int bid = blockIdx.x;
  int swz = (bid & 7) * 64 + (bid >> 3);     // bijective XCD swizzle (512%8==0)
  int qt = swz & 31, h = (swz >> 5) & 7, b = swz >> 8;

  int wave = threadIdx.x >> 6, lane = threadIdx.x & 63;
  int lo = lane & 15, hi = lane >> 4;
  int bh = b * Hh + h;
  size_t base = (size_t)bh * Ss * DKk;
  const char* Krb = (const char*)(kr + base);
  const char* Kpb = (const char*)(kp + base);
  const char* Vrb = (const char*)(vrt + base);
  const char* Vpb = (const char*)(vpt + base);
  const unsigned short* Qr = qr + base;
  const unsigned short* Qp = qp + base;

  // LDS: K dbuf 2x2x8KB + V 2x8KB + P 8KB = 56KB
  __shared__ __align__(16) char kbuf[2][2][8192];
  __shared__ __align__(16) char vbuf[2][8192];
  __shared__ __align__(16) unsigned short plds[4 * 1024];
  char* pbase = (char*)plds + wave * 2048;

  int srow = wave * 8 + (lane >> 3);
  int scol = 16 * ((lane & 7) ^ ((lane >> 3) & 7));
  int lslot = wave * 1024 + lane * 16;

  #define STAGE_T(gbase, rstrideB, ltile)                                    \
    {                                                                        \
      g2l16((gbase) + (size_t)(srow) * (rstrideB) + scol, (ltile) + lslot);  \
      g2l16((gbase) + (size_t)(srow + 32) * (rstrideB) + scol,               \
            (ltile) + 4096 + lslot);                                         \
    }

  int q0 = qt * 64 + wave * 16;
  const unsigned long long* MBq = mb + ((size_t)b * Ss + q0) * 32;

  short8 fqr[2], fqp[2], fqpn[2];
  #pragma unroll
  for (int hf = 0; hf < 2; ++hf) {
    fqr[hf] = *(const short8*)(Qr + (size_t)(q0 + lo) * 64 + 32 * hf + 8 * hi);
    short8 p = *(const short8*)(Qp + (size_t)(q0 + lo) * 64 + 32 * hf + 8 * hi);
    fqp[hf] = p;
    union { short8 s; uint32_t u[4]; } pu; pu.s = p;
    #pragma unroll
    for (int i = 0; i < 4; ++i) pu.u[i] ^= 0x80008000u;
    fqpn[hf] = pu.s;
  }

  f32x4 o_r[4], o_p[4];
  float l_part[4];
  #pragma unroll
  for (int n = 0; n < 4; ++n) { o_r[n] = (f32x4){0,0,0,0}; o_p[n] = (f32x4){0,0,0,0}; }
  #pragma unroll
  for (int r = 0; r < 4; ++r) l_part[r] = 0.f;

  const float inv_scale = 0.08838834764831845f;  // 1/sqrt(2*DK)

  STAGE_T(Krb, 128, kbuf[0][0]);
  STAGE_T(Kpb, 128, kbuf[0][1]);
  __syncthreads();

  int c = 0;
  for (int k0 = 0; k0 < Ss; k0 += 64) {
    STAGE_T(Vrb + (size_t)k0 * 2, 4096, vbuf[0]);
    STAGE_T(Vpb + (size_t)k0 * 2, 4096, vbuf[1]);
    if (k0 + 64 < Ss) {
      STAGE_T(Krb + (size_t)(k0 + 64) * 128, 128, kbuf[c ^ 1][0]);
      STAGE_T(Kpb + (size_t)(k0 + 64) * 128, 128, kbuf[c ^ 1][1]);
    }

    int wq = k0 >> 6;
    unsigned long long mrow[4];
    #pragma unroll
    for (int r = 0; r < 4; ++r) mrow[r] = MBq[(size_t)(4 * hi + r) * 32 + wq];
    unsigned long long andw = mrow[0] & mrow[1] & mrow[2] & mrow[3];
    bool need_mask = !__all((int)(andw == 0xFFFFFFFFFFFFFFFFull));

    const char* Kl = kbuf[c][0];
    const char* Pl = kbuf[c][1];
    f32x4 sre[4], sph[4];
    #pragma unroll
    for (int t = 0; t < 4; ++t) {
      int r0 = 16 * t + lo;
      int sw = (lo & 7) << 4;
      short8 bkr0 = *(const short8*)(Kl + r0 * 128 + ((16 * hi) ^ sw));
      short8 bkr1 = *(const short8*)(Kl + r0 * 128 + ((64 + 16 * hi) ^ sw));
      short8 bkp0 = *(const short8*)(Pl + r0 * 128 + ((16 * hi) ^ sw));
      short8 bkp1 = *(const short8*)(Pl + r0 * 128 + ((64 + 16 * hi) ^ sw));
      f32x4 re = (f32x4){0,0,0,0};
      re = __builtin_amdgcn_mfma_f32_16x16x32_bf16(fqr[0],  bkr0, re, 0,0,0);
      re = __builtin_amdgcn_mfma_f32_16x16x32_bf16(fqr[1],  bkr1, re, 0,0,0);
      re = __builtin_amdgcn_mfma_f32_16x16x32_bf16(fqpn[0], bkp0, re, 0,0,0);
      re = __builtin_amdgcn_mfma_f32_16x16x32_bf16(fqpn[1], bkp1, re, 0,0,0);
      f32x4 ph = (f32x4){0,0,0,0};
      ph = __builtin_amdgcn_mfma_f32_16x16x32_bf16(fqr[0],  bkp0, ph, 0,0,0);
      ph = __builtin_amdgcn_mfma_f32_16x16x32_bf16(fqr[1],  bkp1, ph, 0,0,0);
      ph = __builtin_amdgcn_mfma_f32_16x16x32_bf16(fqp[0],  bkr0, ph, 0,0,0);
      ph = __builtin_amdgcn_mfma_f32_16x16x32_bf16(fqp[1],  bkr1, ph, 0,0,0);
      sre[t] = re; sph[t] = ph;
    }

    float pvals[4][4];
    #pragma unroll
    for (int r = 0; r < 4; ++r) {
      unsigned long long sh = mrow[r] >> lo;
      #pragma unroll
      for (int t = 0; t < 4; ++t) {
        float re = sre[t][r], ph = sph[t][r];
        float v = __builtin_amdgcn_sqrtf(re * re + ph * ph) * inv_scale;
        if (need_mask)
          v = ((unsigned int)(sh >> (16 * t)) & 1u) ? v : -1e9f;
        float p = __expf(v);
        pvals[t][r] = p;
        l_part[r] += p;
      }
    }

    #pragma unroll
    for (int t = 0; t < 4; ++t) {
      #pragma unroll
      for (int r = 0; r < 4; ++r) {
        int row = 4 * hi + r;
        int off = row * 128 + ((((16 * t + lo) * 2) ^ ((row & 7) << 4)));
        *(unsigned short*)(pbase + off) = f2bf(pvals[t][r]);
      }
    }

    __syncthreads();   // barrier A: V[t], K[t+1] landed

    short8 pa[2];
    #pragma unroll
    for (int hf = 0; hf < 2; ++hf) {
      int off = lo * 128 + (((hf * 64 + hi * 16)) ^ ((lo & 7) << 4));
      pa[hf] = *(const short8*)(pbase + off);
    }
    #pragma unroll
    for (int n = 0; n < 4; ++n) {
      int r0 = 16 * n + lo;
      int sw = (lo & 7) << 4;
      short8 bvr0 = *(const short8*)(vbuf[0] + r0 * 128 + ((16 * hi) ^ sw));
      short8 bvr1 = *(const short8*)(vbuf[0] + r0 * 128 + ((64 + 16 * hi) ^ sw));
      short8 bvp0 = *(const short8*)(vbuf[1] + r0 * 128 + ((16 * hi) ^ sw));
      short8 bvp1 = *(const short8*)(vbuf[1] + r0 * 128 + ((64 + 16 * hi) ^ sw));
      o_r[n] = __builtin_amdgcn_mfma_f32_16x16x32_bf16(pa[0], bvr0, o_r[n], 0,0,0);
      o_r[n] = __builtin_amdgcn_mfma_f32_16x16x32_bf16(pa[1], bvr1, o_r[n], 0,0,0);
      o_p[n] = __builtin_amdgcn_mfma_f32_16x16x32_bf16(pa[0], bvp0, o_p[n], 0,0,0);
      o_p[n] = __builtin_amdgcn_mfma_f32_16x16x32_bf16(pa[1], bvp1, o_p[n], 0,0,0);
    }

    __syncthreads();   // barrier B
    c ^= 1;
  }

  #pragma unroll
  for (int r = 0; r < 4; ++r) {
    float v = l_part[r];
    v += __shfl_xor(v, 1);
    v += __shfl_xor(v, 2);
    v += __shfl_xor(v, 4);
    v += __shfl_xor(v, 8);
    l_part[r] = v;
  }
  float invl[4];
  #pragma unroll
  for (int r = 0; r < 4; ++r) invl[r] = 1.f / l_part[r];
  #pragma unroll
  for (int n = 0; n < 4; ++n) {
    #pragma unroll
    for (int r = 0; r < 4; ++r) {
      int q = q0 + 4 * hi + r;
      size_t off = (size_t)(b * Ss + q) * Dd + h * 64 + 16 * n + lo;
      xout[off]         = f2bf(o_r[n][r] * invl[r]);
      xout[MAT_E + off] = f2bf(o_p[n][r] * invl[r]);
    }
  }
  #undef STAGE_T
}

// ---------------- 4. output projection, m97 structure -> fp32 ----------
__global__ __launch_bounds__(256) void ck_out_gemm(
    const unsigned short* __restrict__ x,
    const unsigned short* __restrict__ wot,
    float* __restrict__ out)
{
  int z = blockIdx.z;
  const char* A = (const char*)(x + (size_t)z * MAT_E);
  const char* W = (const char*)wot;
  float* O = out + (size_t)z * MAT_E;

  int tid = threadIdx.x;
  int wave = tid >> 6, lane = tid & 63;
  int lo = lane & 15, hi = lane >> 4;
  int wr = wave >> 1, wc = wave & 1;
  int m0 = blockIdx.x * 128, n0 = blockIdx.y * 128;

  __shared__ __align__(16) char smem[32768];
  char* A0 = smem;          char* A1 = smem + 8192;
  char* B0 = smem + 16384;  char* B1 = smem + 24576;

  int r0s = tid >> 2,  s0s = (tid & 3) ^ ((r0s >> 1) & 3);
  int c1  = 256 + tid;
  int r1s = c1 >> 2,   s1s = (c1 & 3) ^ ((r1s >> 1) & 3);
  int lb0 = wave * 1024;
  int lb1 = 4096 + wave * 1024;

  auto stage = [&](char* Ax, char* Bx, int k0) {
    g2l16(A + (size_t)(m0 + r0s) * 1024 + k0 * 2 + s0s * 16, Ax + lb0);
    g2l16(A + (size_t)(m0 + r1s) * 1024 + k0 * 2 + s1s * 16, Ax + lb1);
    g2l16(W + (size_t)(n0 + r0s) * 1024 + k0 * 2 + s0s * 16, Bx + lb0);
    g2l16(W + (size_t)(n0 + r1s) * 1024 + k0 * 2 + s1s * 16, Bx + lb1);
  };

  f32x4 acc[4][4];
  #pragma unroll
  for (int mf = 0; mf < 4; ++mf)
    #pragma unroll
    for (int nf = 0; nf < 4; ++nf) acc[mf][nf] = (f32x4){0.f, 0.f, 0.f, 0.f};

  int swz = (hi ^ ((lo >> 1) & 3)) * 16;

  auto compute = [&](const char* Ax, const char* Bx) {
    short8 af[4], bf[4];
    #pragma unroll
    for (int mf = 0; mf < 4; ++mf)
      af[mf] = *(const short8*)(Ax + (wr * 64 + mf * 16 + lo) * 64 + swz);
    #pragma unroll
    for (int nf = 0; nf < 4; ++nf)
      bf[nf] = *(const short8*)(Bx + (wc * 64 + nf * 16 + lo) * 64 + swz);
    #pragma unroll
    for (int mf = 0; mf < 4; ++mf)
      #pragma unroll
      for (int nf = 0; nf < 4; ++nf)
        acc[mf][nf] = __builtin_amdgcn_mfma_f32_16x16x32_bf16(af[mf], bf[nf], acc[mf][nf], 0, 0, 0);
  };

  stage(A0, B0, 0);
  __syncthreads();
  #pragma unroll 1
  for (int s = 0; s < 16; s += 2) {
    stage(A1, B1, (s + 1) * 32);
    compute(A0, B0);
    __syncthreads();
    if (s + 2 < 16) stage(A0, B0, (s + 2) * 32);
    compute(A1, B1);
    __syncthreads();
  }

  // direct fp32 store: 16 lanes x 4B = 64B contiguous per fragment row
  #pragma unroll
  for (int mf = 0; mf < 4; ++mf)
    #pragma unroll
    for (int nf = 0; nf < 4; ++nf)
      #pragma unroll
      for (int r = 0; r < 4; ++r) {
        int m = m0 + wr * 64 + mf * 16 + 4 * hi + r;
        int n = n0 + wc * 64 + nf * 16 + lo;
        O[(size_t)m * 512 + n] = acc[mf][nf][r];
      }
}

// ---------------- launch ----------------
extern "C" void kernel_launch(void* const* d_in, const int* in_sizes, int n_in,
                              void* d_out, int out_size, void* d_ws, size_t ws_size,
                              hipStream_t stream) {
  const float* q_real  = (const float*)d_in[0];
  const float* k_real  = (const float*)d_in[1];
  const float* v_real  = (const float*)d_in[2];
  const float* q_phase = (const float*)d_in[3];
  const float* k_phase = (const float*)d_in[4];
  const float* v_phase = (const float*)d_in[5];
  const float* w_q     = (const float*)d_in[6];
  const float* w_k     = (const float*)d_in[7];
  const float* w_v     = (const float*)d_in[8];
  const float* w_o     = (const float*)d_in[9];
  const int*   mask    = (const int*)d_in[10];
  float* out = (float*)d_out;

  unsigned short* ws   = (unsigned short*)d_ws;
  unsigned short* XB   = ws;                            // 6*MAT_E bf16 (dead after proj)
  unsigned short* WT   = ws + 6 * (size_t)MAT_E;        // 4*W_E
  unsigned short* PROJ = WT + 4 * (size_t)W_E;          // 6*MAT_E
  unsigned short* XOUT = PROJ + 6 * (size_t)MAT_E;      // 2*MAT_E
  unsigned long long* MB = (unsigned long long*)XB;     // aliases dead XB

  ck_cvt_in  <<<dim3(2048, 6), 256, 0, stream>>>(q_real, k_real, v_real,
                                                 q_phase, k_phase, v_phase, XB);
  ck_cvt_wt  <<<dim3(1024, 4), 256, 0, stream>>>(w_q, w_k, w_v, w_o, WT);
  ck_proj_gemm<<<dim3(32, 4, 6), 256, 0, stream>>>(XB, WT, PROJ);
  ck_mask_pack<<<dim3(32768), 256, 0, stream>>>(mask, MB);
  ck_attn    <<<dim3(512), 256, 0, stream>>>(PROJ, MB, XOUT);
  ck_out_gemm<<<dim3(32, 4, 2), 256, 0, stream>>>(XOUT, WT + 3 * (size_t)W_E, out);
}